// Round 1
// baseline (182.831 us; speedup 1.0000x reference)
//
#include <hip/hip_runtime.h>

typedef unsigned short u16;
typedef unsigned int u32;

typedef __bf16 bf16x8 __attribute__((ext_vector_type(8)));
typedef float floatx4 __attribute__((ext_vector_type(4)));

// ---- helpers ----------------------------------------------------------------

__device__ __forceinline__ u32 f2bf(float f) {
    // round-to-nearest-even fp32 -> bf16 (bit pattern in low 16)
    u32 u = __builtin_bit_cast(u32, f);
    return (u + 0x7fffu + ((u >> 16) & 1u)) >> 16;
}

__device__ __forceinline__ float quant_w(float x) {
    // WAGE Quantize.W, BITS_W=2: clip to [-0.5,0.5], round to grid step 0.5 (RNE)
    float xc = fminf(fmaxf(x, -0.5f), 0.5f);
    return rintf(xc * 2.0f) * 0.5f;
}

__device__ __forceinline__ u32 cvt_pk_bf16(float lo, float hi) {
    // D[15:0]=bf16(lo), D[31:16]=bf16(hi), RNE (hardware convert; no builtin on gfx950)
    u32 r;
    asm("v_cvt_pk_bf16_f32 %0, %1, %2" : "=v"(r) : "v"(lo), "v"(hi));
    return r;
}

__device__ __forceinline__ void gload_lds16(const u16* g, u16* l) {
    __builtin_amdgcn_global_load_lds(
        (const __attribute__((address_space(1))) void*)g,
        (__attribute__((address_space(3))) void*)l,
        16, 0, 0);
}

// ---- kernel 1: quantize + transpose W[k][n] -> Bt[n][k] bf16 ----------------

__global__ __launch_bounds__(256) void quant_transpose_kernel(const float* __restrict__ W,
                                                              u16* __restrict__ Bt) {
    __shared__ u16 tile[32][33];  // +1 pad: no bank conflicts
    const int KN = 1024;
    int tx = threadIdx.x;  // 0..31
    int ty = threadIdx.y;  // 0..7
    int k0 = blockIdx.y * 32;
    int n0 = blockIdx.x * 32;
#pragma unroll
    for (int i = 0; i < 4; i++) {
        int kl = ty + i * 8;
        float x = W[(k0 + kl) * KN + n0 + tx];
        tile[kl][tx] = (u16)f2bf(quant_w(x));
    }
    __syncthreads();
#pragma unroll
    for (int i = 0; i < 4; i++) {
        int nl = ty + i * 8;
        Bt[(n0 + nl) * KN + k0 + tx] = tile[tx][nl];
    }
}

// ---- kernel 2: fused C[M][N] = cast_bf16(A[M][K]) * Bt[N][K]^T --------------
// 128x128 tile, BK=64 (32 MFMA / barrier).
// B: global_load_lds dwordx4 staging with pre-swizzled global source (linear LDS).
// A: reg-staged fp32 -> v_cvt_pk_bf16_f32 -> swizzled ds_write_b128 (fuses away
//    the separate cast kernel + its 96 MB HBM round-trip). Write slot
//    gc ^ (row&7) matches the read side's chunk ^ (frow&7) XOR bank swizzle.
// grid x = M-blocks so XCD (id%8) gets fixed M-rows; Bt (2 MB) is L2-resident.

__global__ __launch_bounds__(256) void gemm_fused_kernel(const float* __restrict__ A32,
                                                         const u16* __restrict__ Bt,
                                                         float* __restrict__ C) {
    const int K = 1024;
    const int N = 1024;

    __shared__ alignas(16) u16 As[128 * 64];  // 16 KB
    __shared__ alignas(16) u16 Bs[128 * 64];  // 16 KB

    const int tid = threadIdx.x;
    const int mbase = blockIdx.x * 128;
    const int nbase = blockIdx.y * 128;
    const int lane = tid & 63;
    const int wv = tid >> 6;
    const int wm = (wv & 1) * 64;
    const int wn = (wv >> 1) * 64;
    const int frow = lane & 15;           // m (or n) index within 16-tile
    const int fkc = lane >> 4;            // k-chunk index within 32-wide k-step (0..3)
    const int rsw = frow & 7;             // XOR bank swizzle key

    floatx4 acc[4][4] = {};

    // B staging: per call q (0..3), thread t stages chunk c = q*256+t:
    //   LDS (linear, DMA constraint): Bs[c*8 .. c*8+8)
    //   row = q*32 + (t>>3); global k-chunk g8 = (t&7) ^ (row&7)  [bank swizzle]
    const int srow = tid >> 3;
    const int g8 = (tid & 7) ^ (srow & 7);
    const u16* Bga[4];
#pragma unroll
    for (int q = 0; q < 4; q++)
        Bga[q] = &Bt[(size_t)(nbase + q * 32 + srow) * K + g8 * 8];

    // A staging: thread t owns row ar = t>>1, k-half ah = t&1 (32 floats / K-step).
    // chunk c in half -> global chunk gc = ah*4+c -> LDS slot gc ^ (ar&7).
    const int ar = tid >> 1;
    const int ah = tid & 1;
    const float* Ag = &A32[(size_t)(mbase + ar) * K + ah * 32];
    u16* Aw[4];
#pragma unroll
    for (int c = 0; c < 4; c++)
        Aw[c] = &As[ar * 64 + (((ah * 4 + c) ^ (ar & 7)) * 8)];

    for (int kt = 0; kt < K; kt += 64) {
        __syncthreads();  // prior iteration's LDS reads done before overwrite

        // issue B DMA first so it overlaps A's load+cvt
#pragma unroll
        for (int q = 0; q < 4; q++)
            gload_lds16(Bga[q] + kt, &Bs[(q * 256 + tid) * 8]);

        // A: 8x global_load_dwordx4 -> 16x cvt_pk -> 4x ds_write_b128
        float4 av[8];
#pragma unroll
        for (int i = 0; i < 8; i++)
            av[i] = *(const float4*)&Ag[kt + 4 * i];
#pragma unroll
        for (int c = 0; c < 4; c++) {
            uint4 w;
            w.x = cvt_pk_bf16(av[2 * c].x, av[2 * c].y);
            w.y = cvt_pk_bf16(av[2 * c].z, av[2 * c].w);
            w.z = cvt_pk_bf16(av[2 * c + 1].x, av[2 * c + 1].y);
            w.w = cvt_pk_bf16(av[2 * c + 1].z, av[2 * c + 1].w);
            *(uint4*)Aw[c] = w;
        }

        __syncthreads();  // drains vmcnt(0) (B DMA) + lgkmcnt (A ds_write)

#pragma unroll
        for (int s = 0; s < 2; s++) {
            bf16x8 af[4], bf[4];
#pragma unroll
            for (int i = 0; i < 4; i++)
                af[i] = *(const bf16x8*)&As[(wm + i * 16 + frow) * 64 +
                                            (((s * 4 + fkc) ^ rsw) * 8)];
#pragma unroll
            for (int j = 0; j < 4; j++)
                bf[j] = *(const bf16x8*)&Bs[(wn + j * 16 + frow) * 64 +
                                            (((s * 4 + fkc) ^ rsw) * 8)];
#pragma unroll
            for (int i = 0; i < 4; i++)
#pragma unroll
                for (int j = 0; j < 4; j++)
                    acc[i][j] = __builtin_amdgcn_mfma_f32_16x16x32_bf16(
                        af[i], bf[j], acc[i][j], 0, 0, 0);
        }
    }

    // epilogue: C/D layout col = lane&15, row = (lane>>4)*4 + reg
    const int crow = (lane >> 4) * 4;
    const int ccol = lane & 15;
#pragma unroll
    for (int i = 0; i < 4; i++) {
#pragma unroll
        for (int j = 0; j < 4; j++) {
            float* cp = &C[(size_t)(mbase + wm + i * 16 + crow) * N + nbase + wn + j * 16 + ccol];
#pragma unroll
            for (int r = 0; r < 4; r++) cp[r * N] = acc[i][j][r];
        }
    }
}

// ---- launch -----------------------------------------------------------------

extern "C" void kernel_launch(void* const* d_in, const int* in_sizes, int n_in,
                              void* d_out, int out_size, void* d_ws, size_t ws_size,
                              hipStream_t stream) {
    const float* A = (const float*)d_in[0];   // 16384 x 1024 fp32
    const float* W = (const float*)d_in[1];   // 1024 x 1024 fp32
    float* C = (float*)d_out;                 // 16384 x 1024 fp32

    u16* Btq = (u16*)d_ws;                    // 2 MB quantized transposed weights

    quant_transpose_kernel<<<dim3(32, 32), dim3(32, 8), 0, stream>>>(W, Btq);
    gemm_fused_kernel<<<dim3(128, 8), 256, 0, stream>>>(A, Btq, C);
}